// Round 1
// baseline (37146.121 us; speedup 1.0000x reference)
//
#include <hip/hip_runtime.h>
#include <math.h>

// Problem constants (from reference)
#define D_   512   // model dim
#define HH   512   // heads * head_dim
#define NH   8     // heads
#define HD   64    // head dim
#define BQ   512   // batch
#define SS   48    // source length
#define QQ   12    // decode steps
#define LL   4     // layers

// ---------------------------------------------------------------------------
// GEMM: C(M,512) = A(M,512) @ W(512,512) + bias(512), optional ReLU.
// 64x64 tile, BK=16, 256 threads, 4x4 micro-tile per thread. fp32 (no fp32 MFMA).
// ---------------------------------------------------------------------------
__global__ __launch_bounds__(256)
void sgemm_bias(const float* __restrict__ A, const float* __restrict__ W,
                const float* __restrict__ bias, float* __restrict__ C,
                int M, int relu)
{
    __shared__ float As[16][65];   // [k][m], padded
    __shared__ float Bs[16][68];   // [k][n], padded (float4-aligned)

    const int tid = threadIdx.x;
    const int tx  = tid & 15;      // n-group
    const int ty  = tid >> 4;      // m-group
    const int bm  = blockIdx.x;
    const int bn  = blockIdx.y;

    const int a_row = tid >> 2;          // 0..63
    const int a_col = (tid & 3) << 2;    // 0,4,8,12
    const int b_row = tid >> 4;          // 0..15
    const int b_col = (tid & 15) << 2;   // 0..60

    const float* Ap = A + (long)(bm * 64 + a_row) * 512 + a_col;
    const float* Wp = W + (long)b_row * 512 + bn * 64 + b_col;

    float acc[4][4] = {};

    for (int k0 = 0; k0 < 512; k0 += 16) {
        float4 av = *(const float4*)(Ap + k0);
        float4 bv = *(const float4*)(Wp + (long)k0 * 512);
        __syncthreads();
        As[a_col + 0][a_row] = av.x;
        As[a_col + 1][a_row] = av.y;
        As[a_col + 2][a_row] = av.z;
        As[a_col + 3][a_row] = av.w;
        *(float4*)&Bs[b_row][b_col] = bv;
        __syncthreads();
#pragma unroll
        for (int k = 0; k < 16; ++k) {
            float a[4], b[4];
#pragma unroll
            for (int i = 0; i < 4; ++i) a[i] = As[k][ty * 4 + i];
#pragma unroll
            for (int j = 0; j < 4; ++j) b[j] = Bs[k][tx * 4 + j];
#pragma unroll
            for (int i = 0; i < 4; ++i)
#pragma unroll
                for (int j = 0; j < 4; ++j)
                    acc[i][j] = fmaf(a[i], b[j], acc[i][j]);
        }
    }

    float4 bb = *(const float4*)(bias + bn * 64 + tx * 4);
#pragma unroll
    for (int i = 0; i < 4; ++i) {
        float4 o;
        o.x = acc[i][0] + bb.x;
        o.y = acc[i][1] + bb.y;
        o.z = acc[i][2] + bb.z;
        o.w = acc[i][3] + bb.w;
        if (relu) {
            o.x = fmaxf(o.x, 0.f); o.y = fmaxf(o.y, 0.f);
            o.z = fmaxf(o.z, 0.f); o.w = fmaxf(o.w, 0.f);
        }
        *(float4*)(C + (long)(bm * 64 + ty * 4 + i) * 512 + bn * 64 + tx * 4) = o;
    }
}

static inline void gemm(const float* A, const float* W, const float* bias, float* C,
                        int M, int relu, hipStream_t s)
{
    dim3 g(M / 64, 512 / 64);
    sgemm_bias<<<g, 256, 0, s>>>(A, W, bias, C, M, relu);
}

// ---------------------------------------------------------------------------
// Fused attention: one block per (batch, head). Q:(B,Tq,512) K/V:(B,Tk,512)
// scores(Tq,Tk) -> softmax -> out(Tq,64) written into O:(B,Tq,512).
// Tq<=12, Tk<=48. Everything staged in LDS (padded strides).
// ---------------------------------------------------------------------------
__global__ __launch_bounds__(256)
void attn_kernel(const float* __restrict__ Qb, const float* __restrict__ Kb,
                 const float* __restrict__ Vb, float* __restrict__ O,
                 int Tq, int Tk)
{
    __shared__ float Qs[12][65];
    __shared__ float Ks[48][65];
    __shared__ float Vs[48][65];
    __shared__ float Sc[12][49];

    const int blk = blockIdx.x;
    const int b   = blk >> 3;
    const int h   = blk & 7;
    const int tid = threadIdx.x;

    const float* qb = Qb + ((long)b * Tq) * 512 + h * 64;
    const float* kb = Kb + ((long)b * Tk) * 512 + h * 64;
    const float* vb = Vb + ((long)b * Tk) * 512 + h * 64;

    for (int i = tid; i < Tq * 64; i += 256)
        Qs[i >> 6][i & 63] = qb[(long)(i >> 6) * 512 + (i & 63)];
    for (int i = tid; i < Tk * 64; i += 256) {
        Ks[i >> 6][i & 63] = kb[(long)(i >> 6) * 512 + (i & 63)];
        Vs[i >> 6][i & 63] = vb[(long)(i >> 6) * 512 + (i & 63)];
    }
    __syncthreads();

    for (int s = tid; s < Tq * Tk; s += 256) {
        int tq = s / Tk, tk = s - tq * Tk;
        float dot = 0.f;
#pragma unroll 16
        for (int c = 0; c < 64; ++c) dot = fmaf(Qs[tq][c], Ks[tk][c], dot);
        Sc[tq][tk] = dot * 0.125f;   // 1/sqrt(64)
    }
    __syncthreads();

    if (tid < Tq) {
        float mx = -1e30f;
        for (int tk = 0; tk < Tk; ++tk) mx = fmaxf(mx, Sc[tid][tk]);
        float sum = 0.f;
        for (int tk = 0; tk < Tk; ++tk) {
            float e = expf(Sc[tid][tk] - mx);
            Sc[tid][tk] = e;
            sum += e;
        }
        float inv = 1.f / sum;
        for (int tk = 0; tk < Tk; ++tk) Sc[tid][tk] *= inv;
    }
    __syncthreads();

    for (int o = tid; o < Tq * 64; o += 256) {
        int tq = o >> 6, c = o & 63;
        float acc = 0.f;
        for (int tk = 0; tk < Tk; ++tk) acc = fmaf(Sc[tq][tk], Vs[tk][c], acc);
        O[((long)b * Tq + tq) * 512 + h * 64 + c] = acc;
    }
}

// ---------------------------------------------------------------------------
// Fused residual + LayerNorm: Out[row] = LN(A[row] + Hin[row]) * g + b
// One block (256 thr) per row of 512. Two-pass (matches reference var).
// ---------------------------------------------------------------------------
__global__ __launch_bounds__(256)
void add_ln(const float* __restrict__ A, const float* __restrict__ Hin,
            float* __restrict__ Out, const float* __restrict__ g,
            const float* __restrict__ bt)
{
    __shared__ float red[256];
    const int  tid  = threadIdx.x;
    const long base = (long)blockIdx.x * 512 + tid;

    float v0 = A[base] + Hin[base];
    float v1 = A[base + 256] + Hin[base + 256];

    red[tid] = v0 + v1;
    __syncthreads();
    for (int off = 128; off > 0; off >>= 1) {
        if (tid < off) red[tid] += red[tid + off];
        __syncthreads();
    }
    float mu = red[0] * (1.f / 512.f);
    __syncthreads();

    float d0 = v0 - mu, d1 = v1 - mu;
    red[tid] = d0 * d0 + d1 * d1;
    __syncthreads();
    for (int off = 128; off > 0; off >>= 1) {
        if (tid < off) red[tid] += red[tid + off];
        __syncthreads();
    }
    float var = red[0] * (1.f / 512.f);
    float rs  = rsqrtf(var + 1e-6f);

    Out[base]       = d0 * rs * g[tid]       + bt[tid];
    Out[base + 256] = d1 * rs * g[tid + 256] + bt[tid + 256];
}

// ---------------------------------------------------------------------------
// Positional encoding table pe(12,512)
// ---------------------------------------------------------------------------
__global__ void pe_kernel(float* __restrict__ pe)
{
    int i = blockIdx.x * 256 + threadIdx.x;
    if (i >= QQ * D_) return;
    int pos = i / D_, dim = i - pos * D_;
    float e   = 2.f * (float)(dim >> 1) / (float)D_;
    float ang = (float)pos / powf(10000.f, e);
    pe[i] = (dim & 1) ? cosf(ang) : sinf(ang);
}

// ---------------------------------------------------------------------------
// h[b,t,:] = (t==0 ? 0 : out[b,t-1,:]) + pe[t,:]
// ---------------------------------------------------------------------------
__global__ void build_h(const float* __restrict__ out, const float* __restrict__ pe,
                        float* __restrict__ h, int T)
{
    long i = (long)blockIdx.x * 256 + threadIdx.x;
    long total = (long)BQ * T * D_;
    if (i >= total) return;
    int  c   = (int)(i & (D_ - 1));
    long row = i >> 9;            // /512
    int  t   = (int)(row % T);
    long b   = row / T;
    float y  = (t == 0) ? 0.f : out[(b * QQ + (t - 1)) * D_ + c];
    h[i] = y + pe[t * D_ + c];
}

// ---------------------------------------------------------------------------
// out[b,q,:] = sum_{n<T} h[b,n,:] * dw[n] + db
// ---------------------------------------------------------------------------
__global__ void dense_kernel(const float* __restrict__ h, const float* __restrict__ dw,
                             const float* __restrict__ db, float* __restrict__ out,
                             int T, int q)
{
    long i = (long)blockIdx.x * 256 + threadIdx.x;   // over B*512
    if (i >= (long)BQ * D_) return;
    int  c = (int)(i & (D_ - 1));
    long b = i >> 9;
    float acc = db[0];
    for (int n = 0; n < T; ++n) acc = fmaf(h[(b * T + n) * D_ + c], dw[n], acc);
    out[(b * QQ + q) * D_ + c] = acc;
}

// ---------------------------------------------------------------------------
extern "C" void kernel_launch(void* const* d_in, const int* in_sizes, int n_in,
                              void* d_out, int out_size, void* d_ws, size_t ws_size,
                              hipStream_t stream)
{
    const float* x      = (const float*)d_in[0];
    const float* sa_wq  = (const float*)d_in[1];
    const float* sa_bq  = (const float*)d_in[2];
    const float* sa_wk  = (const float*)d_in[3];
    const float* sa_bk  = (const float*)d_in[4];
    const float* sa_wv  = (const float*)d_in[5];
    const float* sa_bv  = (const float*)d_in[6];
    const float* sa_wo  = (const float*)d_in[7];
    const float* sa_bo  = (const float*)d_in[8];
    const float* ca_wq  = (const float*)d_in[9];
    const float* ca_bq  = (const float*)d_in[10];
    const float* ca_wk  = (const float*)d_in[11];
    const float* ca_bk  = (const float*)d_in[12];
    const float* ca_wv  = (const float*)d_in[13];
    const float* ca_bv  = (const float*)d_in[14];
    const float* ca_wo  = (const float*)d_in[15];
    const float* ca_bo  = (const float*)d_in[16];
    const float* ffn_w1 = (const float*)d_in[17];
    const float* ffn_b1 = (const float*)d_in[18];
    const float* ffn_w2 = (const float*)d_in[19];
    const float* ffn_b2 = (const float*)d_in[20];
    const float* ln1_g  = (const float*)d_in[21];
    const float* ln1_b  = (const float*)d_in[22];
    const float* ln2_g  = (const float*)d_in[23];
    const float* ln2_b  = (const float*)d_in[24];
    const float* ln3_g  = (const float*)d_in[25];
    const float* ln3_b  = (const float*)d_in[26];
    const float* dw     = (const float*)d_in[27];
    const float* db     = (const float*)d_in[28];

    float* out = (float*)d_out;
    float* ws  = (float*)d_ws;

    // workspace layout (floats)
    size_t off = 0;
    float* pe = ws + off; off += (size_t)QQ * D_;
    float* h  = ws + off; off += (size_t)BQ * QQ * D_;
    float* tq = ws + off; off += (size_t)BQ * QQ * D_;
    float* ta = ws + off; off += (size_t)BQ * QQ * D_;
    float* t1 = ws + off; off += (size_t)BQ * QQ * D_;
    float* t2 = ws + off; off += (size_t)BQ * QQ * D_;
    float* tk = ws + off; off += (size_t)BQ * SS * D_;
    float* tv = ws + off; off += (size_t)BQ * SS * D_;
    float* kc = ws + off; off += (size_t)LL * BQ * SS * D_;
    float* vc = ws + off; off += (size_t)LL * BQ * SS * D_;
    const bool use_cache = ws_size >= off * sizeof(float);

    pe_kernel<<<(QQ * D_ + 255) / 256, 256, 0, stream>>>(pe);

    if (use_cache) {
        // Cross-attention K/V of static x: compute ONCE per layer (reference
        // recomputes per q-step — this halves total matmul FLOPs).
        for (int l = 0; l < LL; ++l) {
            gemm(x, ca_wk + (size_t)l * D_ * HH, ca_bk + l * HH,
                 kc + (size_t)l * BQ * SS * HH, BQ * SS, 0, stream);
            gemm(x, ca_wv + (size_t)l * D_ * HH, ca_bv + l * HH,
                 vc + (size_t)l * BQ * SS * HH, BQ * SS, 0, stream);
        }
    }

    for (int q = 0; q < QQ; ++q) {
        const int T = q + 1;
        const int M = BQ * T;

        build_h<<<((long)M * D_ + 255) / 256, 256, 0, stream>>>(out, pe, h, T);

        for (int l = 0; l < LL; ++l) {
            const size_t wo_ = (size_t)l * D_ * HH;
            const int    bo_ = l * HH;
            const int    lo_ = l * D_;

            // --- self-attention ---
            gemm(h, sa_wq + wo_, sa_bq + bo_, tq, M, 0, stream);
            gemm(h, sa_wk + wo_, sa_bk + bo_, tk, M, 0, stream);
            gemm(h, sa_wv + wo_, sa_bv + bo_, tv, M, 0, stream);
            attn_kernel<<<BQ * NH, 256, 0, stream>>>(tq, tk, tv, ta, T, T);
            gemm(ta, sa_wo + wo_, sa_bo + bo_, t1, M, 0, stream);
            add_ln<<<M, 256, 0, stream>>>(t1, h, h, ln1_g + lo_, ln1_b + lo_);

            // --- cross-attention ---
            gemm(h, ca_wq + wo_, ca_bq + bo_, tq, M, 0, stream);
            const float *kp, *vp;
            if (use_cache) {
                kp = kc + (size_t)l * BQ * SS * HH;
                vp = vc + (size_t)l * BQ * SS * HH;
            } else {
                gemm(x, ca_wk + wo_, ca_bk + bo_, tk, BQ * SS, 0, stream);
                gemm(x, ca_wv + wo_, ca_bv + bo_, tv, BQ * SS, 0, stream);
                kp = tk; vp = tv;
            }
            attn_kernel<<<BQ * NH, 256, 0, stream>>>(tq, kp, vp, ta, T, SS);
            gemm(ta, ca_wo + wo_, ca_bo + bo_, t1, M, 0, stream);
            add_ln<<<M, 256, 0, stream>>>(t1, h, h, ln2_g + lo_, ln2_b + lo_);

            // --- FFN ---
            gemm(h, ffn_w1 + wo_, ffn_b1 + lo_, t2, M, 1, stream);
            gemm(t2, ffn_w2 + wo_, ffn_b2 + lo_, t1, M, 0, stream);
            add_ln<<<M, 256, 0, stream>>>(t1, h, h, ln3_g + lo_, ln3_b + lo_);
        }

        dense_kernel<<<(BQ * D_ + 255) / 256, 256, 0, stream>>>(h, dw, db, out, T, q);
    }
}

// Round 2
// 24618.304 us; speedup vs baseline: 1.5089x; 1.5089x over previous
//
#include <hip/hip_runtime.h>
#include <math.h>

// Problem constants
#define D_   512
#define NH   8
#define BQ   512
#define SS   48
#define QQ   12
#define LL   4
#define MMAX (BQ * QQ)        // 6144 max rows

typedef __attribute__((ext_vector_type(8))) short s16x8;
typedef __attribute__((ext_vector_type(4))) float f32x4;
typedef unsigned short u16;

// bf16 helpers (RNE)
__device__ __forceinline__ u16 f2bf(float x) {
    union { float f; unsigned u; } v; v.f = x;
    unsigned r = v.u + 0x7fffu + ((v.u >> 16) & 1u);
    return (u16)(r >> 16);
}
__device__ __forceinline__ float bf2f(u16 b) {
    union { float f; unsigned u; } v; v.u = ((unsigned)b) << 16;
    return v.f;
}

// packed-weight geometry (ushort units)
#define QKV_SZ   (3 * 64 * 1536 * 8)
#define CAQ_OFF  QKV_SZ
#define CAKV_OFF (CAQ_OFF + 3 * 64 * 512 * 8)
#define SAO_OFF  (CAKV_OFF + 3 * 64 * 1024 * 8)
#define CAO_OFF  (SAO_OFF + 3 * 64 * 512 * 8)
#define F1_OFF   (CAO_OFF + 3 * 64 * 512 * 8)
#define F2_OFF   (F1_OFF + 3 * 64 * 512 * 8)
#define LPACK    (F2_OFF + 3 * 64 * 512 * 8)   // 7,864,320 ushorts / layer

// ---------------------------------------------------------------------------
// Pre-pack weights: W[l](512 k x N cols) fp32 -> 3-split bf16 [s][g][n][8k]
// ---------------------------------------------------------------------------
__global__ __launch_bounds__(256)
void pack_weights(const float* __restrict__ s0, const float* __restrict__ s1,
                  const float* __restrict__ s2, const float* __restrict__ s3,
                  const float* __restrict__ s4, const float* __restrict__ s5,
                  const float* __restrict__ s6, const float* __restrict__ s7,
                  const float* __restrict__ s8, const float* __restrict__ s9,
                  u16* __restrict__ PACK)
{
    const int id    = blockIdx.y;       // 0..39
    const int mat   = id >> 2;
    const int layer = id & 3;
    const int idx   = blockIdx.x * 256 + threadIdx.x;   // 0..32767
    const int n     = idx & 511;
    const int g     = idx >> 9;         // k-group 0..63

    const float* srcs[10] = {s0, s1, s2, s3, s4, s5, s6, s7, s8, s9};
    const int dstoff[10] = {0, 0, 0, CAQ_OFF, CAKV_OFF, CAKV_OFF,
                            SAO_OFF, CAO_OFF, F1_OFF, F2_OFF};
    const int ntot[10] = {1536, 1536, 1536, 512, 1024, 1024, 512, 512, 512, 512};
    const int noff[10] = {0, 512, 1024, 0, 0, 512, 0, 0, 0, 0};

    const float* src = srcs[mat] + (size_t)layer * 512 * 512;
    const int Ntot = ntot[mat];
    const size_t SPS = (size_t)64 * Ntot * 8;   // split stride

    s16x8 vh, vm, vl;
#pragma unroll
    for (int e = 0; e < 8; ++e) {
        float x = src[(size_t)(g * 8 + e) * 512 + n];
        u16 hh = f2bf(x); float r = x - bf2f(hh);
        u16 mm = f2bf(r); r -= bf2f(mm);
        vh[e] = (short)hh; vm[e] = (short)mm; vl[e] = (short)f2bf(r);
    }
    u16* d = PACK + (size_t)layer * LPACK + dstoff[mat]
           + ((size_t)g * Ntot + noff[mat] + n) * 8;
    *(s16x8*)(d)           = vh;
    *(s16x8*)(d + SPS)     = vm;
    *(s16x8*)(d + 2 * SPS) = vl;
}

__global__ void pack_bias(const float* __restrict__ sbq, const float* __restrict__ sbk,
                          const float* __restrict__ sbv, const float* __restrict__ cbk,
                          const float* __restrict__ cbv, float* __restrict__ qkvb,
                          float* __restrict__ cakvb)
{
    int i = blockIdx.x * 256 + threadIdx.x;
    if (i < 4 * 1536) {
        int l = i / 1536, c = i - l * 1536;
        float v = (c < 512) ? sbq[l * 512 + c]
                : (c < 1024) ? sbk[l * 512 + c - 512] : sbv[l * 512 + c - 1024];
        qkvb[i] = v;
    } else if (i < 4 * 1536 + 4 * 1024) {
        int j = i - 4 * 1536;
        int l = j / 1024, c = j - l * 1024;
        cakvb[j] = (c < 512) ? cbk[l * 512 + c] : cbv[l * 512 + c - 512];
    }
}

// ---------------------------------------------------------------------------
// GEMM via 3-split bf16 MFMA: C(M,N) = A(M,512) @ W + bias, optional ReLU.
// Tile 128x128xBK32, 256 thr (4 waves), wave -> 64x64, mfma_f32_16x16x32_bf16,
// 6 products (hh,hm,mh,hl,mm,lh) -> fp32-accurate. XOR-swizzled LDS.
// ---------------------------------------------------------------------------
__global__ __launch_bounds__(256, 2)
void gemm3s(const float* __restrict__ A, const u16* __restrict__ PW,
            const float* __restrict__ bias, float* __restrict__ C,
            int M, int N, int relu)
{
    __shared__ __align__(16) u16 As[3][4096];
    __shared__ __align__(16) u16 Bs[3][4096];

    const int tid = threadIdx.x;
    const int bm = blockIdx.x, bn = blockIdx.y;
    const int l  = tid & 63;
    const int wv = tid >> 6;
    const int wm = (wv >> 1) * 64, wn = (wv & 1) * 64;

    f32x4 acc[4][4] = {};

    // staging: unit = (row, kgroup); thread handles rows r0 and r0+64, group g0
    const int r0 = tid >> 2, g0 = tid & 3;
    const int eo0 = ((r0 * 32 + g0 * 8) ^ ((r0 & 7) << 3));
    const int eo1 = eo0 + 64 * 32;

    const float* a0 = A + (size_t)(bm * 128 + r0) * 512 + g0 * 8;
    const float* a1 = a0 + (size_t)64 * 512;
    const size_t SPS = (size_t)64 * N * 8;

    for (int ks = 0; ks < 16; ++ks) {
        const int k0 = ks * 32;
        // global loads (A fp32, B pre-split bf16)
        float4 av00 = *(const float4*)(a0 + k0);
        float4 av01 = *(const float4*)(a0 + k0 + 4);
        float4 av10 = *(const float4*)(a1 + k0);
        float4 av11 = *(const float4*)(a1 + k0 + 4);
        const u16* pb = PW + ((size_t)((k0 >> 3) + g0) * N + bn * 128 + r0) * 8;
        s16x8 b00 = *(const s16x8*)(pb);
        s16x8 b01 = *(const s16x8*)(pb + SPS);
        s16x8 b02 = *(const s16x8*)(pb + 2 * SPS);
        s16x8 b10 = *(const s16x8*)(pb + (size_t)64 * 8);
        s16x8 b11 = *(const s16x8*)(pb + (size_t)64 * 8 + SPS);
        s16x8 b12 = *(const s16x8*)(pb + (size_t)64 * 8 + 2 * SPS);

        __syncthreads();   // previous iteration's frag reads done

        // convert A -> 3 splits, write LDS
        {
            float va[8] = {av00.x, av00.y, av00.z, av00.w, av01.x, av01.y, av01.z, av01.w};
            s16x8 vh, vm2, vl2;
#pragma unroll
            for (int e = 0; e < 8; ++e) {
                u16 hh = f2bf(va[e]); float r = va[e] - bf2f(hh);
                u16 mm = f2bf(r); r -= bf2f(mm);
                vh[e] = (short)hh; vm2[e] = (short)mm; vl2[e] = (short)f2bf(r);
            }
            *(s16x8*)&As[0][eo0] = vh; *(s16x8*)&As[1][eo0] = vm2; *(s16x8*)&As[2][eo0] = vl2;
        }
        {
            float va[8] = {av10.x, av10.y, av10.z, av10.w, av11.x, av11.y, av11.z, av11.w};
            s16x8 vh, vm2, vl2;
#pragma unroll
            for (int e = 0; e < 8; ++e) {
                u16 hh = f2bf(va[e]); float r = va[e] - bf2f(hh);
                u16 mm = f2bf(r); r -= bf2f(mm);
                vh[e] = (short)hh; vm2[e] = (short)mm; vl2[e] = (short)f2bf(r);
            }
            *(s16x8*)&As[0][eo1] = vh; *(s16x8*)&As[1][eo1] = vm2; *(s16x8*)&As[2][eo1] = vl2;
        }
        *(s16x8*)&Bs[0][eo0] = b00; *(s16x8*)&Bs[1][eo0] = b01; *(s16x8*)&Bs[2][eo0] = b02;
        *(s16x8*)&Bs[0][eo1] = b10; *(s16x8*)&Bs[1][eo1] = b11; *(s16x8*)&Bs[2][eo1] = b12;

        __syncthreads();

        // A fragments: all splits, 4 m-subtiles
        s16x8 af[3][4];
#pragma unroll
        for (int i = 0; i < 4; ++i) {
            int row = wm + i * 16 + (l & 15);
            int eo  = ((row * 32 + (l >> 4) * 8) ^ ((row & 7) << 3));
            af[0][i] = *(const s16x8*)&As[0][eo];
            af[1][i] = *(const s16x8*)&As[1][eo];
            af[2][i] = *(const s16x8*)&As[2][eo];
        }
#pragma unroll
        for (int j = 0; j < 4; ++j) {
            int nn = wn + j * 16 + (l & 15);
            int eo = ((nn * 32 + (l >> 4) * 8) ^ ((nn & 7) << 3));
            s16x8 bf0 = *(const s16x8*)&Bs[0][eo];
            s16x8 bf1 = *(const s16x8*)&Bs[1][eo];
            s16x8 bf2 = *(const s16x8*)&Bs[2][eo];
#pragma unroll
            for (int i = 0; i < 4; ++i) {
                acc[i][j] = __builtin_amdgcn_mfma_f32_16x16x32_bf16(af[0][i], bf0, acc[i][j], 0, 0, 0);
                acc[i][j] = __builtin_amdgcn_mfma_f32_16x16x32_bf16(af[0][i], bf1, acc[i][j], 0, 0, 0);
                acc[i][j] = __builtin_amdgcn_mfma_f32_16x16x32_bf16(af[1][i], bf0, acc[i][j], 0, 0, 0);
                acc[i][j] = __builtin_amdgcn_mfma_f32_16x16x32_bf16(af[0][i], bf2, acc[i][j], 0, 0, 0);
                acc[i][j] = __builtin_amdgcn_mfma_f32_16x16x32_bf16(af[1][i], bf1, acc[i][j], 0, 0, 0);
                acc[i][j] = __builtin_amdgcn_mfma_f32_16x16x32_bf16(af[2][i], bf0, acc[i][j], 0, 0, 0);
            }
        }
    }

    // epilogue: C/D map col=lane&15, row=(lane>>4)*4+r
#pragma unroll
    for (int i = 0; i < 4; ++i) {
        int row = bm * 128 + wm + i * 16 + (l >> 4) * 4;
#pragma unroll
        for (int j = 0; j < 4; ++j) {
            int col = bn * 128 + wn + j * 16 + (l & 15);
            float bb = bias[col];
#pragma unroll
            for (int r = 0; r < 4; ++r) {
                float v = acc[i][j][r] + bb;
                if (relu) v = fmaxf(v, 0.f);
                C[(size_t)(row + r) * N + col] = v;
            }
        }
    }
}

static inline void gemm(const float* A, const u16* PW, const float* bias, float* C,
                        int M, int N, int relu, hipStream_t s)
{
    dim3 g(M / 128, N / 128);
    gemm3s<<<g, 256, 0, s>>>(A, PW, bias, C, M, N, relu);
}

// ---------------------------------------------------------------------------
// Fused attention with strides. One block per (batch, head).
// ---------------------------------------------------------------------------
__global__ __launch_bounds__(256)
void attn_kernel(const float* __restrict__ Qb, int qstride,
                 const float* __restrict__ Kb, const float* __restrict__ Vb, int kvstride,
                 float* __restrict__ O, int Tq, int Tk)
{
    __shared__ float Qs[12][65];
    __shared__ float Ks[48][65];
    __shared__ float Vs[48][65];
    __shared__ float Sc[12][49];

    const int blk = blockIdx.x;
    const int b   = blk >> 3;
    const int h   = blk & 7;
    const int tid = threadIdx.x;

    const float* qb = Qb + (size_t)b * Tq * qstride + h * 64;
    const float* kb = Kb + (size_t)b * Tk * kvstride + h * 64;
    const float* vb = Vb + (size_t)b * Tk * kvstride + h * 64;

    for (int i = tid; i < Tq * 64; i += 256)
        Qs[i >> 6][i & 63] = qb[(size_t)(i >> 6) * qstride + (i & 63)];
    for (int i = tid; i < Tk * 64; i += 256) {
        Ks[i >> 6][i & 63] = kb[(size_t)(i >> 6) * kvstride + (i & 63)];
        Vs[i >> 6][i & 63] = vb[(size_t)(i >> 6) * kvstride + (i & 63)];
    }
    __syncthreads();

    for (int s = tid; s < Tq * Tk; s += 256) {
        int tq = s / Tk, tk = s - tq * Tk;
        float dot = 0.f;
#pragma unroll 16
        for (int c = 0; c < 64; ++c) dot = fmaf(Qs[tq][c], Ks[tk][c], dot);
        Sc[tq][tk] = dot * 0.125f;
    }
    __syncthreads();

    if (tid < Tq) {
        float mx = -1e30f;
        for (int tk = 0; tk < Tk; ++tk) mx = fmaxf(mx, Sc[tid][tk]);
        float sum = 0.f;
        for (int tk = 0; tk < Tk; ++tk) {
            float e = expf(Sc[tid][tk] - mx);
            Sc[tid][tk] = e; sum += e;
        }
        float inv = 1.f / sum;
        for (int tk = 0; tk < Tk; ++tk) Sc[tid][tk] *= inv;
    }
    __syncthreads();

    for (int o = tid; o < Tq * 64; o += 256) {
        int tq = o >> 6, c = o & 63;
        float a = 0.f;
        for (int tk = 0; tk < Tk; ++tk) a = fmaf(Sc[tq][tk], Vs[tk][c], a);
        O[((size_t)b * Tq + tq) * 512 + h * 64 + c] = a;
    }
}

// ---------------------------------------------------------------------------
__global__ __launch_bounds__(256)
void add_ln(const float* __restrict__ A, const float* __restrict__ Hin,
            float* __restrict__ Out, const float* __restrict__ g,
            const float* __restrict__ bt)
{
    __shared__ float red[256];
    const int  tid  = threadIdx.x;
    const size_t base = (size_t)blockIdx.x * 512 + tid;

    float v0 = A[base] + Hin[base];
    float v1 = A[base + 256] + Hin[base + 256];

    red[tid] = v0 + v1;
    __syncthreads();
    for (int off = 128; off > 0; off >>= 1) {
        if (tid < off) red[tid] += red[tid + off];
        __syncthreads();
    }
    float mu = red[0] * (1.f / 512.f);
    __syncthreads();

    float d0 = v0 - mu, d1 = v1 - mu;
    red[tid] = d0 * d0 + d1 * d1;
    __syncthreads();
    for (int off = 128; off > 0; off >>= 1) {
        if (tid < off) red[tid] += red[tid + off];
        __syncthreads();
    }
    float var = red[0] * (1.f / 512.f);
    float rs  = rsqrtf(var + 1e-6f);

    Out[base]       = d0 * rs * g[tid]       + bt[tid];
    Out[base + 256] = d1 * rs * g[tid + 256] + bt[tid + 256];
}

__global__ void pe_kernel(float* __restrict__ pe)
{
    int i = blockIdx.x * 256 + threadIdx.x;
    if (i >= QQ * D_) return;
    int pos = i / D_, dim = i - pos * D_;
    float e   = 2.f * (float)(dim >> 1) / (float)D_;
    float ang = (float)pos / powf(10000.f, e);
    pe[i] = (dim & 1) ? cosf(ang) : sinf(ang);
}

__global__ void build_h(const float* __restrict__ out, const float* __restrict__ pe,
                        float* __restrict__ h, int T)
{
    size_t i = (size_t)blockIdx.x * 256 + threadIdx.x;
    size_t total = (size_t)BQ * T * D_;
    if (i >= total) return;
    int  c   = (int)(i & (D_ - 1));
    size_t row = i >> 9;
    int  t   = (int)(row % T);
    size_t b = row / T;
    float y  = (t == 0) ? 0.f : out[(b * QQ + (t - 1)) * D_ + c];
    h[i] = y + pe[t * D_ + c];
}

__global__ void dense_kernel(const float* __restrict__ h, const float* __restrict__ dw,
                             const float* __restrict__ db, float* __restrict__ out,
                             int T, int q)
{
    size_t i = (size_t)blockIdx.x * 256 + threadIdx.x;
    if (i >= (size_t)BQ * D_) return;
    int  c = (int)(i & (D_ - 1));
    size_t b = i >> 9;
    float acc = db[0];
    for (int n = 0; n < T; ++n) acc = fmaf(h[(b * T + n) * D_ + c], dw[n], acc);
    out[(b * QQ + q) * D_ + c] = acc;
}

// ---------------------------------------------------------------------------
extern "C" void kernel_launch(void* const* d_in, const int* in_sizes, int n_in,
                              void* d_out, int out_size, void* d_ws, size_t ws_size,
                              hipStream_t stream)
{
    const float* x      = (const float*)d_in[0];
    const float* sa_wq  = (const float*)d_in[1];
    const float* sa_bq  = (const float*)d_in[2];
    const float* sa_wk  = (const float*)d_in[3];
    const float* sa_bk  = (const float*)d_in[4];
    const float* sa_wv  = (const float*)d_in[5];
    const float* sa_bv  = (const float*)d_in[6];
    const float* sa_wo  = (const float*)d_in[7];
    const float* sa_bo  = (const float*)d_in[8];
    const float* ca_wq  = (const float*)d_in[9];
    const float* ca_bq  = (const float*)d_in[10];
    const float* ca_wk  = (const float*)d_in[11];
    const float* ca_bk  = (const float*)d_in[12];
    const float* ca_wv  = (const float*)d_in[13];
    const float* ca_bv  = (const float*)d_in[14];
    const float* ca_wo  = (const float*)d_in[15];
    const float* ca_bo  = (const float*)d_in[16];
    const float* ffn_w1 = (const float*)d_in[17];
    const float* ffn_b1 = (const float*)d_in[18];
    const float* ffn_w2 = (const float*)d_in[19];
    const float* ffn_b2 = (const float*)d_in[20];
    const float* ln1_g  = (const float*)d_in[21];
    const float* ln1_b  = (const float*)d_in[22];
    const float* ln2_g  = (const float*)d_in[23];
    const float* ln2_b  = (const float*)d_in[24];
    const float* ln3_g  = (const float*)d_in[25];
    const float* ln3_b  = (const float*)d_in[26];
    const float* dw     = (const float*)d_in[27];
    const float* db     = (const float*)d_in[28];

    float* out = (float*)d_out;
    float* ws  = (float*)d_ws;

    // ws layout (float units)
    size_t off = 0;
    float* pe   = ws + off; off += QQ * D_;
    float* h    = ws + off; off += (size_t)MMAX * 512;
    float* big  = ws + off; off += (size_t)MMAX * 1536;   // tqkv; aliased t1/t2/tq
    float* ta   = ws + off; off += (size_t)MMAX * 512;
    float* qkvb = ws + off; off += 4 * 1536;
    float* cakvb= ws + off; off += 4 * 1024;
    off = (off + 3) & ~(size_t)3;                          // 16B align
    u16* PACK = (u16*)(ws + off); off += (size_t)4 * LPACK / 2;
    size_t base_need = off;
    float* kvc = ws + off;
    size_t full_need = off + (size_t)LL * BQ * SS * 1024;
    const bool use_cache = ws_size >= full_need * sizeof(float);
    float* kvtmp = kvc;   // fallback single-layer buffer (if !use_cache)
    (void)base_need;

    float* t1 = big;
    float* t2 = big + (size_t)MMAX * 512;
    float* tq = big + (size_t)2 * MMAX * 512;

    // --- pre-pack (every call: ws is re-poisoned) ---
    pack_weights<<<dim3(128, 40), 256, 0, stream>>>(
        sa_wq, sa_wk, sa_wv, ca_wq, ca_wk, ca_wv, sa_wo, ca_wo, ffn_w1, ffn_w2, PACK);
    pack_bias<<<40, 256, 0, stream>>>(sa_bq, sa_bk, sa_bv, ca_bk, ca_bv, qkvb, cakvb);
    pe_kernel<<<(QQ * D_ + 255) / 256, 256, 0, stream>>>(pe);

    const u16* PQKV[LL]; const u16* PCAQ[LL]; const u16* PCAKV[LL];
    const u16* PSAO[LL]; const u16* PCAO[LL]; const u16* PF1[LL]; const u16* PF2[LL];
    for (int l = 0; l < LL; ++l) {
        u16* base = PACK + (size_t)l * LPACK;
        PQKV[l] = base;            PCAQ[l] = base + CAQ_OFF;
        PCAKV[l] = base + CAKV_OFF; PSAO[l] = base + SAO_OFF;
        PCAO[l] = base + CAO_OFF;  PF1[l] = base + F1_OFF;  PF2[l] = base + F2_OFF;
    }

    if (use_cache) {
        for (int l = 0; l < LL; ++l)
            gemm(x, PCAKV[l], cakvb + l * 1024, kvc + (size_t)l * BQ * SS * 1024,
                 BQ * SS, 1024, 0, stream);
    }

    for (int q = 0; q < QQ; ++q) {
        const int T = q + 1;
        const int M = BQ * T;

        build_h<<<((size_t)M * D_ + 255) / 256, 256, 0, stream>>>(out, pe, h, T);

        for (int l = 0; l < LL; ++l) {
            // --- self-attention (fused QKV) ---
            gemm(h, PQKV[l], qkvb + l * 1536, big, M, 1536, 0, stream);
            attn_kernel<<<BQ * NH, 256, 0, stream>>>(big, 1536, big + 512, big + 1024, 1536,
                                                     ta, T, T);
            gemm(ta, PSAO[l], sa_bo + l * 512, t1, M, 512, 0, stream);
            add_ln<<<M, 256, 0, stream>>>(t1, h, h, ln1_g + l * 512, ln1_b + l * 512);

            // --- cross-attention ---
            gemm(h, PCAQ[l], ca_bq + l * 512, tq, M, 512, 0, stream);
            const float* kv;
            if (use_cache) {
                kv = kvc + (size_t)l * BQ * SS * 1024;
            } else {
                gemm(x, PCAKV[l], cakvb + l * 1024, kvtmp, BQ * SS, 1024, 0, stream);
                kv = kvtmp;
            }
            attn_kernel<<<BQ * NH, 256, 0, stream>>>(tq, 512, kv, kv + 512, 1024,
                                                     ta, T, SS);
            gemm(ta, PCAO[l], ca_bo + l * 512, t1, M, 512, 0, stream);
            add_ln<<<M, 256, 0, stream>>>(t1, h, h, ln2_g + l * 512, ln2_b + l * 512);

            // --- FFN ---
            gemm(h, PF1[l], ffn_b1 + l * 512, t2, M, 512, 1, stream);
            gemm(t2, PF2[l], ffn_b2 + l * 512, t1, M, 512, 0, stream);
            add_ln<<<M, 256, 0, stream>>>(t1, h, h, ln3_g + l * 512, ln3_b + l * 512);
        }

        dense_kernel<<<(BQ * D_ + 255) / 256, 256, 0, stream>>>(h, dw, db, out, T, q);
    }
}